// Round 5
// baseline (2356.129 us; speedup 1.0000x reference)
//
#include <hip/hip_runtime.h>

// PhysicsRULModel fully-fused kernel for MI355X (gfx950).  R4.
// grid = B = 256 (1 block/CU), block = 512 (8 waves/CU).
// R3 was LDS-issue-bound (~2000 LDS-pipe cyc/step: 16 b128 + 10 swizzle per
// lane). R4 cuts LDS ~4x via column-block ownership:
//   waves 0-3 (h0-waves): lane=(unit s, quarter q) owns 8 rows x 16-col
//     quarter (Whh0 i,f,g,o rows + Wih1 i,f,g,o rows of unit s) -> reads ONE
//     h0 quarter (4 b128) per step for 128 FMAs.
//   waves 4-7 (h1-waves): 4 Whh1 rows x quarter -> 4 b128 for 64 FMAs.
//     L1 lags 2 steps; Wih1 partial sums flow h0->h1 waves via small LDS
//     buffer (stride-1), double-buffered => still 1 barrier/step.
//   Quarter reduction + gate gather via quad_perm DPP (VALU, no LDS).
// Skews: gates0(u) from h0(u-1); L1 step t=u-2: hh from h1(u-3), ih-partials
// (written at iter t+1) from LDS. h1(t) lands at iter t+2 -> epilogue at
// u==2 (mod 16), t0=u-18.

#define Bn 256
#define Tn 2048
#define Hn 64
#define CH 16
#define NT 512

__device__ __forceinline__ float rcpf_(float x) { return __builtin_amdgcn_rcpf(x); }
__device__ __forceinline__ float tanhf2_(float x) {
    float e = __expf(2.0f * x);
    return 1.0f - 2.0f * rcpf_(e + 1.0f);
}
// quad_perm DPP helpers (pure VALU; no LDS pipe)
#define DPPF(v, ctrl) __int_as_float(__builtin_amdgcn_update_dpp(0, __float_as_int(v), (ctrl), 0xF, 0xF, true))
#define QSUM(v) { v += DPPF(v, 0xB1); v += DPPF(v, 0x4E); }   // full sum over quad, all 4 lanes
#define DOT2(acc, w_, x_) { acc.x = fmaf((w_).x, (x_).x, acc.x); acc.y = fmaf((w_).y, (x_).y, acc.y); }

__device__ __forceinline__ float sel4_(float a0, float a1, float a2, float a3, int q) {
    float v = (q & 1) ? a1 : a0;
    float w = (q & 1) ? a3 : a2;
    return (q & 2) ? w : v;
}

__global__ __launch_bounds__(512, 1)
void fused_rul_kernel(
    const float* __restrict__ ts,   const float* __restrict__ sf,
    const float* __restrict__ Wih0, const float* __restrict__ Whh0,
    const float* __restrict__ bih0, const float* __restrict__ bhh0,
    const float* __restrict__ Wih1, const float* __restrict__ Whh1,
    const float* __restrict__ bih1, const float* __restrict__ bhh1,
    const float* __restrict__ seW1, const float* __restrict__ seb1,
    const float* __restrict__ seW2, const float* __restrict__ seb2,
    const float* __restrict__ pbW1, const float* __restrict__ pbb1,
    const float* __restrict__ pbW2, const float* __restrict__ pbb2,
    const float* __restrict__ pbW3, const float* __restrict__ pbb3,
    const float* __restrict__ drW1, const float* __restrict__ drb1,
    const float* __restrict__ drW2, const float* __restrict__ drb2,
    const float* __restrict__ drW3, const float* __restrict__ drb3,
    const float* __restrict__ ruW1, const float* __restrict__ rub1,
    const float* __restrict__ ruW2, const float* __restrict__ rub2,
    float* __restrict__ out)
{
    const int tid  = threadIdx.x;
    const int b    = blockIdx.x;
    const int lane = tid & 63;
    const int w    = tid >> 6;          // wave 0..7
    const bool isH0 = (w < 4);
    const int q    = lane & 3;          // quarter 0..3 (cols 16q..16q+15)
    const int s    = ((w & 3) << 4) | (lane >> 2);   // unit/slot 0..63

    // ---- LDS ----
    __shared__ __align__(16) float h0s[2][Hn];
    __shared__ __align__(16) float h1s[2][Hn];
    __shared__ __align__(16) float g1ih[2][Hn][4];   // L1 ih partial gates [buf][unit][gate]
    __shared__ __align__(16) float h1ring[CH][Hn];
    __shared__ float tempc[CH];
    __shared__ __align__(16) float ssb[CH][32];
    __shared__ __align__(16) float se1b[CH][32];
    __shared__ __align__(16) float dr1b[CH][Hn];
    __shared__ float degb[CH];
    __shared__ float hltb[CH];
    // MLP weight tables: pitch == 2 (mod 32) -> conflict-free float2 reads
    __shared__ __align__(16) float seW1L[32 * 66];
    __shared__ __align__(16) float seW2L[32 * 34];
    __shared__ __align__(16) float drW1L[64 * 34];
    __shared__ __align__(8)  float drW1t[3][64];
    __shared__ __align__(16) float drW2L[32 * 66];
    __shared__ __align__(16) float ruW1L[32 * 34];
    __shared__ float ruW1t[32];
    __shared__ float seb1L[32], seb2L[32], drb1L[64], drb2L[32], drW3L[32];
    __shared__ float rub1L[32], ruW2L[32];
    __shared__ float phys_s[4];
    __shared__ float drb3_s, rub2_s;

    // ---- cooperative LDS weight staging ----
    for (int i = tid; i < 32 * 64; i += NT) { int rr = i >> 6, c = i & 63; seW1L[rr * 66 + c] = seW1[i]; }
    for (int i = tid; i < 32 * 32; i += NT) { int rr = i >> 5, c = i & 31; seW2L[rr * 34 + c] = seW2[i]; }
    for (int i = tid; i < 64 * 32; i += NT) { int rr = i >> 5, c = i & 31; drW1L[rr * 34 + c] = drW1[rr * 35 + c]; }
    if (tid < 192) { int k = tid >> 6, rr = tid & 63; drW1t[k][rr] = drW1[rr * 35 + 32 + k]; }
    for (int i = tid; i < 32 * 64; i += NT) { int rr = i >> 6, c = i & 63; drW2L[rr * 66 + c] = drW2[i]; }
    for (int i = tid; i < 32 * 32; i += NT) { int rr = i >> 5, c = i & 31; ruW1L[rr * 34 + c] = ruW1[rr * 33 + c]; }
    if (tid < 32) {
        ruW1t[tid] = ruW1[tid * 33 + 32];
        seb1L[tid] = seb1[tid]; seb2L[tid] = seb2[tid]; drb2L[tid] = drb2[tid];
        drW3L[tid] = drW3[tid]; rub1L[tid] = rub1[tid]; ruW2L[tid] = ruW2[tid];
    }
    if (tid < 64) drb1L[tid] = drb1[tid];
    if (tid == 0) { drb3_s = drb3[0]; rub2_s = rub2[0]; }

    // ---- physics branch (tiny MLP, thread 0) ----
    if (tid == 0) {
        float p1[32];
        for (int o = 0; o < 32; ++o) {
            float a = pbb1[o];
            for (int k = 0; k < 3; ++k) a += pbW1[o * 3 + k] * sf[b * 3 + k];
            p1[o] = fmaxf(a, 0.f);
        }
        float p2[16];
        for (int o = 0; o < 16; ++o) {
            float a = pbb2[o];
            for (int k = 0; k < 32; ++k) a += pbW2[o * 32 + k] * p1[k];
            p2[o] = fmaxf(a, 0.f);
        }
        float Ea = pbb3[0], lA = pbb3[1];
        for (int k = 0; k < 16; ++k) { Ea += pbW3[k] * p2[k]; lA += pbW3[16 + k] * p2[k]; }
        phys_s[0] = __expf(lA);
        phys_s[1] = -Ea * 1000.0f / 8.314f;
        phys_s[2] = Ea;
        phys_s[3] = lA;
    }

    // ---- LSTM weights into VGPRs: 8 (h0-waves) / 4 (h1-waves) quarter-rows ----
    float4 wa[16], wb[16];       // wa: Whh0 (h0) or Whh1 (h1); wb: Wih1 (h0 only)
    float bact, wi0a = 0.f, wi0b = 0.f;
    {
        const int rq = (q << 6) + s;          // activation row this lane owns
        if (isH0) {
            #pragma unroll
            for (int g4 = 0; g4 < 4; ++g4) {
                const int row = (g4 << 6) + s;
                const float4* pa = (const float4*)(Whh0 + row * 64 + q * 16);
                const float4* pb = (const float4*)(Wih1 + row * 64 + q * 16);
                #pragma unroll
                for (int k = 0; k < 4; ++k) { wa[g4 * 4 + k] = pa[k]; wb[g4 * 4 + k] = pb[k]; }
            }
            bact = bih0[rq] + bhh0[rq];
            wi0a = Wih0[rq * 2 + 0]; wi0b = Wih0[rq * 2 + 1];
        } else {
            #pragma unroll
            for (int g4 = 0; g4 < 4; ++g4) {
                const int row = (g4 << 6) + s;
                const float4* pa = (const float4*)(Whh1 + row * 64 + q * 16);
                #pragma unroll
                for (int k = 0; k < 4; ++k) wa[g4 * 4 + k] = pa[k];
            }
            bact = bih1[rq] + bhh1[rq];
        }
    }
    // activation constants for gate q: sig for i,f,o; tanh for g (q==2)
    const bool  isg  = (q == 2);
    const float kmul = isg ? 2.f : -1.f;
    const float kk   = isg ? -2.f : 1.f;
    const float cc   = isg ? 1.f : 0.f;

    float cst = 0.f;              // c0 (h0-lanes) or c1 (h1-lanes) for unit s
    float hst = 1.0f;
    float xprev = 0.f, xprev2 = 0.f;
    if (tid < 64) { h0s[0][tid] = 0.f; h0s[1][tid] = 0.f; h1s[0][tid] = 0.f; h1s[1][tid] = 0.f; }
    __syncthreads();

    const float* tsb  = ts + (size_t)b * Tn * 2;
    float* outR = out + (size_t)b * Tn;
    float* outD = out + (size_t)Bn * Tn + (size_t)b * Tn;
    float* outH = out + 2 * (size_t)Bn * Tn + (size_t)b * Tn;

    #pragma unroll 1
    for (int u = 0; u <= Tn + 2; ++u) {
        float2 xv = make_float2(0.f, 0.f);
        if (isH0 && u < Tn) xv = *(const float2*)(tsb + 2 * u);

        // ---------- epilogue for completed chunk (h1(t) lands at iter t+2) ----------
        if ((u & (CH - 1)) == 2 && u >= 18) {
            const int t0 = u - 18;
            {   // se1
                const int pos = tid >> 5, jj = tid & 31;
                float2 acc = make_float2(0.f, 0.f);
                const float2* wr = (const float2*)(seW1L + jj * 66);
                const float2* hr = (const float2*)(&h1ring[pos][0]);
                #pragma unroll
                for (int k = 0; k < 32; ++k) { float2 ww = wr[k], hh = hr[k]; DOT2(acc, ww, hh); }
                se1b[pos][jj] = fmaxf(acc.x + acc.y + seb1L[jj], 0.f);
            }
            __syncthreads();
            {   // se2
                const int pos = tid >> 5, jj = tid & 31;
                float2 acc = make_float2(0.f, 0.f);
                const float2* wr = (const float2*)(seW2L + jj * 34);
                const float2* xr = (const float2*)(&se1b[pos][0]);
                #pragma unroll
                for (int k = 0; k < 16; ++k) { float2 ww = wr[k], xx = xr[k]; DOT2(acc, ww, xx); }
                ssb[pos][jj] = acc.x + acc.y + seb2L[jj];
            }
            __syncthreads();
            {   // dr1
                const int jj = tid & 63;
                const float2* wr = (const float2*)(drW1L + jj * 34);
                const float w32 = drW1t[0][jj], w33 = drW1t[1][jj], w34 = drW1t[2][jj];
                const float bb = drb1L[jj];
                const float ea_ = phys_s[2], la_ = phys_s[3];
                #pragma unroll
                for (int rep = 0; rep < 2; ++rep) {
                    const int pos = (tid >> 6) + rep * 8;
                    float2 acc = make_float2(0.f, 0.f);
                    const float2* xr = (const float2*)(&ssb[pos][0]);
                    #pragma unroll
                    for (int k = 0; k < 16; ++k) { float2 ww = wr[k], xx = xr[k]; DOT2(acc, ww, xx); }
                    float a = acc.x + acc.y + bb + w32 * tempc[pos] + w33 * ea_ + w34 * la_;
                    dr1b[pos][jj] = fmaxf(a, 0.f);
                }
            }
            __syncthreads();
            {   // dr2 + dr3 fused
                const int pos = tid >> 5, jj = tid & 31;
                float2 acc = make_float2(0.f, 0.f);
                const float2* wr = (const float2*)(drW2L + jj * 66);
                const float2* xr = (const float2*)(&dr1b[pos][0]);
                #pragma unroll
                for (int k = 0; k < 32; ++k) { float2 ww = wr[k], xx = xr[k]; DOT2(acc, ww, xx); }
                float p = drW3L[jj] * fmaxf(acc.x + acc.y + drb2L[jj], 0.f);
                #pragma unroll
                for (int off = 16; off > 0; off >>= 1) p += __shfl_down(p, off, 32);
                if (jj == 0) degb[pos] = p + drb3_s;
            }
            __syncthreads();
            if (tid == 0) {   // health scan
                const float Af = phys_s[0], ne = phys_s[1];
                #pragma unroll
                for (int p2 = 0; p2 < CH; ++p2) {
                    float tK  = tempc[p2] + 273.15f;
                    float arr = Af * __expf(ne * rcpf_(tK));
                    float comb = 0.7f * degb[p2] + 0.3f * arr;
                    hst = fminf(fmaxf(hst - comb, 0.f), 1.f);
                    hltb[p2] = hst;
                }
            }
            __syncthreads();
            {   // rul head + outputs
                const int pos = tid >> 5, jj = tid & 31;
                float2 acc = make_float2(0.f, 0.f);
                const float2* wr = (const float2*)(ruW1L + jj * 34);
                const float2* xr = (const float2*)(&ssb[pos][0]);
                #pragma unroll
                for (int k = 0; k < 16; ++k) { float2 ww = wr[k], xx = xr[k]; DOT2(acc, ww, xx); }
                float a = acc.x + acc.y + rub1L[jj] + ruW1t[jj] * hltb[pos];
                float p = ruW2L[jj] * fmaxf(a, 0.f);
                #pragma unroll
                for (int off = 16; off > 0; off >>= 1) p += __shfl_down(p, off, 32);
                if (jj == 0) outR[t0 + pos] = fmaxf(p + rub2_s, 0.f);
            }
            if (tid < CH) { outD[t0 + tid] = degb[tid]; outH[t0 + tid] = hltb[tid]; }
        }

        // ---------- LSTM step ----------
        if (isH0) {
            if (u <= Tn) {
                // read h0(u-1) quarter q  (buffer (u-1)&1 == (u+1)&1)
                const float4* hq = (const float4*)(&h0s[(u + 1) & 1][q * 16]);
                float4 h0q0 = hq[0], h0q1 = hq[1], h0q2 = hq[2], h0q3 = hq[3];
                float SA[4] = {0.f, 0.f, 0.f, 0.f};   // Whh0 rows i,f,g,o
                float SB[4] = {0.f, 0.f, 0.f, 0.f};   // Wih1 rows i,f,g,o
                #pragma unroll
                for (int g4 = 0; g4 < 4; ++g4) {
                    float4 wk;
                    wk = wa[g4 * 4 + 0]; SA[g4] = fmaf(wk.x, h0q0.x, fmaf(wk.y, h0q0.y, fmaf(wk.z, h0q0.z, fmaf(wk.w, h0q0.w, SA[g4]))));
                    wk = wa[g4 * 4 + 1]; SA[g4] = fmaf(wk.x, h0q1.x, fmaf(wk.y, h0q1.y, fmaf(wk.z, h0q1.z, fmaf(wk.w, h0q1.w, SA[g4]))));
                    wk = wa[g4 * 4 + 2]; SA[g4] = fmaf(wk.x, h0q2.x, fmaf(wk.y, h0q2.y, fmaf(wk.z, h0q2.z, fmaf(wk.w, h0q2.w, SA[g4]))));
                    wk = wa[g4 * 4 + 3]; SA[g4] = fmaf(wk.x, h0q3.x, fmaf(wk.y, h0q3.y, fmaf(wk.z, h0q3.z, fmaf(wk.w, h0q3.w, SA[g4]))));
                    wk = wb[g4 * 4 + 0]; SB[g4] = fmaf(wk.x, h0q0.x, fmaf(wk.y, h0q0.y, fmaf(wk.z, h0q0.z, fmaf(wk.w, h0q0.w, SB[g4]))));
                    wk = wb[g4 * 4 + 1]; SB[g4] = fmaf(wk.x, h0q1.x, fmaf(wk.y, h0q1.y, fmaf(wk.z, h0q1.z, fmaf(wk.w, h0q1.w, SB[g4]))));
                    wk = wb[g4 * 4 + 2]; SB[g4] = fmaf(wk.x, h0q2.x, fmaf(wk.y, h0q2.y, fmaf(wk.z, h0q2.z, fmaf(wk.w, h0q2.w, SB[g4]))));
                    wk = wb[g4 * 4 + 3]; SB[g4] = fmaf(wk.x, h0q3.x, fmaf(wk.y, h0q3.y, fmaf(wk.z, h0q3.z, fmaf(wk.w, h0q3.w, SB[g4]))));
                }
                QSUM(SA[0]); QSUM(SA[1]); QSUM(SA[2]); QSUM(SA[3]);
                QSUM(SB[0]); QSUM(SB[1]); QSUM(SB[2]); QSUM(SB[3]);
                if (u < Tn) {
                    // layer0 gate q of unit s
                    float val = sel4_(SA[0], SA[1], SA[2], SA[3], q);
                    val = fmaf(wi0a, xv.x, fmaf(wi0b, xv.y, val + bact));
                    float act = fmaf(rcpf_(1.f + __expf(kmul * val)), kk, cc);
                    float gi = DPPF(act, 0x00), gf = DPPF(act, 0x55), gg = DPPF(act, 0xAA), go = DPPF(act, 0xFF);
                    cst = fmaf(gf, cst, gi * gg);
                    float h0new = go * tanhf2_(cst);
                    if (q == 0) h0s[u & 1][s] = h0new;
                }
                if (u >= 1) {
                    // L1 ih partial for step t = u-1 -> buffer (u-1)&1 == (u+1)&1
                    g1ih[(u + 1) & 1][s][q] = sel4_(SB[0], SB[1], SB[2], SB[3], q);
                }
            }
            if (tid == 0 && u >= 2 && u <= Tn + 1) tempc[(u - 2) & (CH - 1)] = xprev2;
        } else {
            if (u >= 2 && u <= Tn + 1) {
                // L1 step t = u-2: hh dot on h1(u-3) (buffer (u-3)&1 == (u+1)&1)
                const float4* hq = (const float4*)(&h1s[(u + 1) & 1][q * 16]);
                float4 h1q0 = hq[0], h1q1 = hq[1], h1q2 = hq[2], h1q3 = hq[3];
                float SA[4] = {0.f, 0.f, 0.f, 0.f};
                #pragma unroll
                for (int g4 = 0; g4 < 4; ++g4) {
                    float4 wk;
                    wk = wa[g4 * 4 + 0]; SA[g4] = fmaf(wk.x, h1q0.x, fmaf(wk.y, h1q0.y, fmaf(wk.z, h1q0.z, fmaf(wk.w, h1q0.w, SA[g4]))));
                    wk = wa[g4 * 4 + 1]; SA[g4] = fmaf(wk.x, h1q1.x, fmaf(wk.y, h1q1.y, fmaf(wk.z, h1q1.z, fmaf(wk.w, h1q1.w, SA[g4]))));
                    wk = wa[g4 * 4 + 2]; SA[g4] = fmaf(wk.x, h1q2.x, fmaf(wk.y, h1q2.y, fmaf(wk.z, h1q2.z, fmaf(wk.w, h1q2.w, SA[g4]))));
                    wk = wa[g4 * 4 + 3]; SA[g4] = fmaf(wk.x, h1q3.x, fmaf(wk.y, h1q3.y, fmaf(wk.z, h1q3.z, fmaf(wk.w, h1q3.w, SA[g4]))));
                }
                QSUM(SA[0]); QSUM(SA[1]); QSUM(SA[2]); QSUM(SA[3]);
                // ih partial for t=u-2 from buffer (u-2)&1 == u&1
                float pt = g1ih[u & 1][s][q];
                float val = sel4_(SA[0], SA[1], SA[2], SA[3], q) + pt + bact;
                float act = fmaf(rcpf_(1.f + __expf(kmul * val)), kk, cc);
                float gi = DPPF(act, 0x00), gf = DPPF(act, 0x55), gg = DPPF(act, 0xAA), go = DPPF(act, 0xFF);
                cst = fmaf(gf, cst, gi * gg);
                float h1new = go * tanhf2_(cst);
                if (q == 0) h1s[u & 1][s] = h1new;                 // buffer (u-2)&1
                if (q == 1) h1ring[(u - 2) & (CH - 1)][s] = h1new;
            }
        }
        xprev2 = xprev; xprev = xv.x;
        __syncthreads();
    }
}

extern "C" void kernel_launch(void* const* d_in, const int* in_sizes, int n_in,
                              void* d_out, int out_size, void* d_ws, size_t ws_size,
                              hipStream_t stream) {
    const float* ts   = (const float*)d_in[0];
    const float* sf   = (const float*)d_in[1];
    const float* Wih0 = (const float*)d_in[2];
    const float* Whh0 = (const float*)d_in[3];
    const float* bih0 = (const float*)d_in[4];
    const float* bhh0 = (const float*)d_in[5];
    const float* Wih1 = (const float*)d_in[6];
    const float* Whh1 = (const float*)d_in[7];
    const float* bih1 = (const float*)d_in[8];
    const float* bhh1 = (const float*)d_in[9];
    const float* seW1 = (const float*)d_in[10];
    const float* seb1 = (const float*)d_in[11];
    const float* seW2 = (const float*)d_in[12];
    const float* seb2 = (const float*)d_in[13];
    const float* pbW1 = (const float*)d_in[14];
    const float* pbb1 = (const float*)d_in[15];
    const float* pbW2 = (const float*)d_in[16];
    const float* pbb2 = (const float*)d_in[17];
    const float* pbW3 = (const float*)d_in[18];
    const float* pbb3 = (const float*)d_in[19];
    const float* drW1 = (const float*)d_in[20];
    const float* drb1 = (const float*)d_in[21];
    const float* drW2 = (const float*)d_in[22];
    const float* drb2 = (const float*)d_in[23];
    const float* drW3 = (const float*)d_in[24];
    const float* drb3 = (const float*)d_in[25];
    const float* ruW1 = (const float*)d_in[26];
    const float* rub1 = (const float*)d_in[27];
    const float* ruW2 = (const float*)d_in[28];
    const float* rub2 = (const float*)d_in[29];
    float* out = (float*)d_out;

    fused_rul_kernel<<<dim3(Bn), dim3(NT), 0, stream>>>(
        ts, sf, Wih0, Whh0, bih0, bhh0, Wih1, Whh1, bih1, bhh1,
        seW1, seb1, seW2, seb2, pbW1, pbb1, pbW2, pbb2, pbW3, pbb3,
        drW1, drb1, drW2, drb2, drW3, drb3, ruW1, rub1, ruW2, rub2, out);
}

// Round 6
// 2053.487 us; speedup vs baseline: 1.1474x; 1.1474x over previous
//
#include <hip/hip_runtime.h>

// PhysicsRULModel fully-fused kernel for MI355X (gfx950).  R5.
// grid = B = 256 (1 block/CU), block = 512 (8 waves/CU).
// R4 post-mortem: WRITE_SIZE doubled -> compiler capped VGPRs at 128 and
// spilled the 128-reg weight array on h0-waves. R5:
//  - weight ownership rebalanced to 96 VGPRs/lane:
//      h0-lane: Whh0 quarter-rows (i,f,g,o) + Wih1 quarter-rows (i,f)
//      h1-lane: Whh1 quarter-rows (i,f,g,o) + Wih1 quarter-rows (g,o)
//    h1-waves read the h0(u-2) quarter directly; h0s is TRIPLE-buffered so
//    the concurrent h0(u) write never races the h0(u-1)/h0(u-2) reads.
//    Wih1(i,f) partials pass h0->h1 waves via g1ih[2][64][2] (double-buffered).
//  - all LSTM dots use v_pk_fma_f32 (inline asm): 96 scalar FMA -> 48 packed.
//  - __launch_bounds__(512,2): VGPR budget 256 (2 waves/SIMD), no spills.
// Skews (as R4): L0 step u at iter u from h0(u-1); L1 step t=u-2 from
// h1(u-3), h0(u-2), partials written at iter u-1. h1(t) lands at iter t+2
// -> epilogue at u==2 (mod 16), t0=u-18. tempc[(u-2)&15]=x(u-2) at iter u.

#define Bn 256
#define Tn 2048
#define Hn 64
#define CH 16
#define NT 512

typedef float f32x2 __attribute__((ext_vector_type(2)));

__device__ __forceinline__ float rcpf_(float x) { return __builtin_amdgcn_rcpf(x); }
__device__ __forceinline__ float tanhf2_(float x) {
    float e = __expf(2.0f * x);
    return 1.0f - 2.0f * rcpf_(e + 1.0f);
}
// packed fp32 FMA: acc = w*x + acc  (one VOP3P instr, 2 FMAs)
__device__ __forceinline__ void pkfma(f32x2& acc, f32x2 w, f32x2 x) {
    asm("v_pk_fma_f32 %0, %1, %2, %0" : "+v"(acc) : "v"(w), "v"(x));
}
// quad_perm DPP helpers (pure VALU; no LDS pipe)
#define DPPF(v, ctrl) __int_as_float(__builtin_amdgcn_update_dpp(0, __float_as_int(v), (ctrl), 0xF, 0xF, true))
#define QSUM(v) { v += DPPF(v, 0xB1); v += DPPF(v, 0x4E); }
#define DOT2(acc, w_, x_) { acc.x = fmaf((w_).x, (x_).x, acc.x); acc.y = fmaf((w_).y, (x_).y, acc.y); }

__device__ __forceinline__ float sel4_(float a0, float a1, float a2, float a3, int q) {
    float v = (q & 1) ? a1 : a0;
    float w = (q & 1) ? a3 : a2;
    return (q & 2) ? w : v;
}

__global__ __launch_bounds__(512, 2)
void fused_rul_kernel(
    const float* __restrict__ ts,   const float* __restrict__ sf,
    const float* __restrict__ Wih0, const float* __restrict__ Whh0,
    const float* __restrict__ bih0, const float* __restrict__ bhh0,
    const float* __restrict__ Wih1, const float* __restrict__ Whh1,
    const float* __restrict__ bih1, const float* __restrict__ bhh1,
    const float* __restrict__ seW1, const float* __restrict__ seb1,
    const float* __restrict__ seW2, const float* __restrict__ seb2,
    const float* __restrict__ pbW1, const float* __restrict__ pbb1,
    const float* __restrict__ pbW2, const float* __restrict__ pbb2,
    const float* __restrict__ pbW3, const float* __restrict__ pbb3,
    const float* __restrict__ drW1, const float* __restrict__ drb1,
    const float* __restrict__ drW2, const float* __restrict__ drb2,
    const float* __restrict__ drW3, const float* __restrict__ drb3,
    const float* __restrict__ ruW1, const float* __restrict__ rub1,
    const float* __restrict__ ruW2, const float* __restrict__ rub2,
    float* __restrict__ out)
{
    const int tid  = threadIdx.x;
    const int b    = blockIdx.x;
    const int lane = tid & 63;
    const int w    = tid >> 6;          // wave 0..7
    const bool isH0 = (w < 4);
    const int q    = lane & 3;          // quarter 0..3 (cols 16q..16q+15)
    const int s    = ((w & 3) << 4) | (lane >> 2);   // unit/slot 0..63

    // ---- LDS ----
    __shared__ __align__(16) float h0s[3][Hn];       // triple-buffered
    __shared__ __align__(16) float h1s[2][Hn];
    __shared__ __align__(16) float g1ih[2][Hn][2];   // L1 ih partials (i,f) [buf][unit][gate]
    __shared__ __align__(16) float h1ring[CH][Hn];
    __shared__ float tempc[CH];
    __shared__ __align__(16) float ssb[CH][32];
    __shared__ __align__(16) float se1b[CH][32];
    __shared__ __align__(16) float dr1b[CH][Hn];
    __shared__ float degb[CH];
    __shared__ float hltb[CH];
    // MLP weight tables: pitch == 2 (mod 32) -> conflict-free float2 reads
    __shared__ __align__(16) float seW1L[32 * 66];
    __shared__ __align__(16) float seW2L[32 * 34];
    __shared__ __align__(16) float drW1L[64 * 34];
    __shared__ __align__(8)  float drW1t[3][64];
    __shared__ __align__(16) float drW2L[32 * 66];
    __shared__ __align__(16) float ruW1L[32 * 34];
    __shared__ float ruW1t[32];
    __shared__ float seb1L[32], seb2L[32], drb1L[64], drb2L[32], drW3L[32];
    __shared__ float rub1L[32], ruW2L[32];
    __shared__ float phys_s[4];
    __shared__ float drb3_s, rub2_s;

    // ---- cooperative LDS weight staging ----
    for (int i = tid; i < 32 * 64; i += NT) { int rr = i >> 6, c = i & 63; seW1L[rr * 66 + c] = seW1[i]; }
    for (int i = tid; i < 32 * 32; i += NT) { int rr = i >> 5, c = i & 31; seW2L[rr * 34 + c] = seW2[i]; }
    for (int i = tid; i < 64 * 32; i += NT) { int rr = i >> 5, c = i & 31; drW1L[rr * 34 + c] = drW1[rr * 35 + c]; }
    if (tid < 192) { int k = tid >> 6, rr = tid & 63; drW1t[k][rr] = drW1[rr * 35 + 32 + k]; }
    for (int i = tid; i < 32 * 64; i += NT) { int rr = i >> 6, c = i & 63; drW2L[rr * 66 + c] = drW2[i]; }
    for (int i = tid; i < 32 * 32; i += NT) { int rr = i >> 5, c = i & 31; ruW1L[rr * 34 + c] = ruW1[rr * 33 + c]; }
    if (tid < 32) {
        ruW1t[tid] = ruW1[tid * 33 + 32];
        seb1L[tid] = seb1[tid]; seb2L[tid] = seb2[tid]; drb2L[tid] = drb2[tid];
        drW3L[tid] = drW3[tid]; rub1L[tid] = rub1[tid]; ruW2L[tid] = ruW2[tid];
    }
    if (tid < 64) drb1L[tid] = drb1[tid];
    if (tid == 0) { drb3_s = drb3[0]; rub2_s = rub2[0]; }

    // ---- physics branch (tiny MLP, thread 0) ----
    if (tid == 0) {
        float p1[32];
        for (int o = 0; o < 32; ++o) {
            float a = pbb1[o];
            for (int k = 0; k < 3; ++k) a += pbW1[o * 3 + k] * sf[b * 3 + k];
            p1[o] = fmaxf(a, 0.f);
        }
        float p2[16];
        for (int o = 0; o < 16; ++o) {
            float a = pbb2[o];
            for (int k = 0; k < 32; ++k) a += pbW2[o * 32 + k] * p1[k];
            p2[o] = fmaxf(a, 0.f);
        }
        float Ea = pbb3[0], lA = pbb3[1];
        for (int k = 0; k < 16; ++k) { Ea += pbW3[k] * p2[k]; lA += pbW3[16 + k] * p2[k]; }
        phys_s[0] = __expf(lA);
        phys_s[1] = -Ea * 1000.0f / 8.314f;
        phys_s[2] = Ea;
        phys_s[3] = lA;
    }

    // ---- LSTM weights into VGPRs (96 regs/lane) ----
    // wA: 4 gate-rows of Whh0 (h0-waves) / Whh1 (h1-waves), quarter q.
    // wB: 2 gate-rows of Wih1, quarter q: gates (i,f) on h0-waves, (g,o) on h1.
    f32x2 wA[32], wB[16];
    float bact, wi0a = 0.f, wi0b = 0.f;
    {
        const int rq = (q << 6) + s;          // activation row this lane owns
        const float* WAsrc = isH0 ? Whh0 : Whh1;
        const int gB0 = isH0 ? 0 : 2;
        #pragma unroll
        for (int g4 = 0; g4 < 4; ++g4) {
            const f32x2* pa = (const f32x2*)(WAsrc + ((g4 << 6) + s) * 64 + q * 16);
            #pragma unroll
            for (int k = 0; k < 8; ++k) wA[g4 * 8 + k] = pa[k];
        }
        #pragma unroll
        for (int g4 = 0; g4 < 2; ++g4) {
            const f32x2* pb = (const f32x2*)(Wih1 + (((gB0 + g4) << 6) + s) * 64 + q * 16);
            #pragma unroll
            for (int k = 0; k < 8; ++k) wB[g4 * 8 + k] = pb[k];
        }
        if (isH0) {
            bact = bih0[rq] + bhh0[rq];
            wi0a = Wih0[rq * 2 + 0]; wi0b = Wih0[rq * 2 + 1];
        } else {
            bact = bih1[rq] + bhh1[rq];
        }
    }
    // activation constants for gate q: sig for i,f,o; tanh for g (q==2)
    const bool  isg  = (q == 2);
    const float kmul = isg ? 2.f : -1.f;
    const float kk   = isg ? -2.f : 1.f;
    const float cc   = isg ? 1.f : 0.f;

    float cst = 0.f;              // c0 (h0-lanes) / c1 (h1-lanes) for unit s
    float hst = 1.0f;
    float xprev = 0.f, xprev2 = 0.f;
    if (tid < 64) {
        h0s[0][tid] = 0.f; h0s[1][tid] = 0.f; h0s[2][tid] = 0.f;
        h1s[0][tid] = 0.f; h1s[1][tid] = 0.f;
    }
    __syncthreads();

    const float* tsb  = ts + (size_t)b * Tn * 2;
    float* outR = out + (size_t)b * Tn;
    float* outD = out + (size_t)Bn * Tn + (size_t)b * Tn;
    float* outH = out + 2 * (size_t)Bn * Tn + (size_t)b * Tn;

    // h0s rotating slots: sW = slot of h0(u), s1 = h0(u-1), s2 = h0(u-2)
    int sW = 0, s1 = 2, s2 = 1;

    #pragma unroll 1
    for (int u = 0; u <= Tn + 2; ++u) {
        float2 xv = make_float2(0.f, 0.f);
        if (isH0 && u < Tn) xv = *(const float2*)(tsb + 2 * u);

        // ---------- epilogue for completed chunk (h1(t) lands at iter t+2) ----------
        if ((u & (CH - 1)) == 2 && u >= 18) {
            const int t0 = u - 18;
            {   // se1
                const int pos = tid >> 5, jj = tid & 31;
                float2 acc = make_float2(0.f, 0.f);
                const float2* wr = (const float2*)(seW1L + jj * 66);
                const float2* hr = (const float2*)(&h1ring[pos][0]);
                #pragma unroll
                for (int k = 0; k < 32; ++k) { float2 ww = wr[k], hh = hr[k]; DOT2(acc, ww, hh); }
                se1b[pos][jj] = fmaxf(acc.x + acc.y + seb1L[jj], 0.f);
            }
            __syncthreads();
            {   // se2
                const int pos = tid >> 5, jj = tid & 31;
                float2 acc = make_float2(0.f, 0.f);
                const float2* wr = (const float2*)(seW2L + jj * 34);
                const float2* xr = (const float2*)(&se1b[pos][0]);
                #pragma unroll
                for (int k = 0; k < 16; ++k) { float2 ww = wr[k], xx = xr[k]; DOT2(acc, ww, xx); }
                ssb[pos][jj] = acc.x + acc.y + seb2L[jj];
            }
            __syncthreads();
            {   // dr1
                const int jj = tid & 63;
                const float2* wr = (const float2*)(drW1L + jj * 34);
                const float w32 = drW1t[0][jj], w33 = drW1t[1][jj], w34 = drW1t[2][jj];
                const float bb = drb1L[jj];
                const float ea_ = phys_s[2], la_ = phys_s[3];
                #pragma unroll
                for (int rep = 0; rep < 2; ++rep) {
                    const int pos = (tid >> 6) + rep * 8;
                    float2 acc = make_float2(0.f, 0.f);
                    const float2* xr = (const float2*)(&ssb[pos][0]);
                    #pragma unroll
                    for (int k = 0; k < 16; ++k) { float2 ww = wr[k], xx = xr[k]; DOT2(acc, ww, xx); }
                    float a = acc.x + acc.y + bb + w32 * tempc[pos] + w33 * ea_ + w34 * la_;
                    dr1b[pos][jj] = fmaxf(a, 0.f);
                }
            }
            __syncthreads();
            {   // dr2 + dr3 fused
                const int pos = tid >> 5, jj = tid & 31;
                float2 acc = make_float2(0.f, 0.f);
                const float2* wr = (const float2*)(drW2L + jj * 66);
                const float2* xr = (const float2*)(&dr1b[pos][0]);
                #pragma unroll
                for (int k = 0; k < 32; ++k) { float2 ww = wr[k], xx = xr[k]; DOT2(acc, ww, xx); }
                float p = drW3L[jj] * fmaxf(acc.x + acc.y + drb2L[jj], 0.f);
                #pragma unroll
                for (int off = 16; off > 0; off >>= 1) p += __shfl_down(p, off, 32);
                if (jj == 0) degb[pos] = p + drb3_s;
            }
            __syncthreads();
            if (tid == 0) {   // health scan
                const float Af = phys_s[0], ne = phys_s[1];
                #pragma unroll
                for (int p2 = 0; p2 < CH; ++p2) {
                    float tK  = tempc[p2] + 273.15f;
                    float arr = Af * __expf(ne * rcpf_(tK));
                    float comb = 0.7f * degb[p2] + 0.3f * arr;
                    hst = fminf(fmaxf(hst - comb, 0.f), 1.f);
                    hltb[p2] = hst;
                }
            }
            __syncthreads();
            {   // rul head + outputs
                const int pos = tid >> 5, jj = tid & 31;
                float2 acc = make_float2(0.f, 0.f);
                const float2* wr = (const float2*)(ruW1L + jj * 34);
                const float2* xr = (const float2*)(&ssb[pos][0]);
                #pragma unroll
                for (int k = 0; k < 16; ++k) { float2 ww = wr[k], xx = xr[k]; DOT2(acc, ww, xx); }
                float a = acc.x + acc.y + rub1L[jj] + ruW1t[jj] * hltb[pos];
                float p = ruW2L[jj] * fmaxf(a, 0.f);
                #pragma unroll
                for (int off = 16; off > 0; off >>= 1) p += __shfl_down(p, off, 32);
                if (jj == 0) outR[t0 + pos] = fmaxf(p + rub2_s, 0.f);
            }
            if (tid < CH) { outD[t0 + tid] = degb[tid]; outH[t0 + tid] = hltb[tid]; }
        }

        // ---------- LSTM step ----------
        if (isH0) {
            if (u <= Tn) {
                // read h0(u-1) quarter q
                const float4* hv4 = (const float4*)(&h0s[s1][q * 16]);
                f32x2 A0 = {0,0}, A1 = {0,0}, A2 = {0,0}, A3 = {0,0}, B0 = {0,0}, B1 = {0,0};
                #pragma unroll
                for (int k = 0; k < 4; ++k) {
                    float4 h4 = hv4[k];
                    f32x2 lo = {h4.x, h4.y}, hi = {h4.z, h4.w};
                    pkfma(A0, wA[0  + 2*k], lo); pkfma(A0, wA[1  + 2*k], hi);
                    pkfma(A1, wA[8  + 2*k], lo); pkfma(A1, wA[9  + 2*k], hi);
                    pkfma(A2, wA[16 + 2*k], lo); pkfma(A2, wA[17 + 2*k], hi);
                    pkfma(A3, wA[24 + 2*k], lo); pkfma(A3, wA[25 + 2*k], hi);
                    pkfma(B0, wB[0  + 2*k], lo); pkfma(B0, wB[1  + 2*k], hi);
                    pkfma(B1, wB[8  + 2*k], lo); pkfma(B1, wB[9  + 2*k], hi);
                }
                float Sa0 = A0.x + A0.y, Sa1 = A1.x + A1.y, Sa2 = A2.x + A2.y, Sa3 = A3.x + A3.y;
                float Sb0 = B0.x + B0.y, Sb1 = B1.x + B1.y;
                QSUM(Sa0); QSUM(Sa1); QSUM(Sa2); QSUM(Sa3);
                QSUM(Sb0); QSUM(Sb1);
                if (u < Tn) {
                    float val = sel4_(Sa0, Sa1, Sa2, Sa3, q);
                    val = fmaf(wi0a, xv.x, fmaf(wi0b, xv.y, val + bact));
                    float act = fmaf(rcpf_(1.f + __expf(kmul * val)), kk, cc);
                    float gi = DPPF(act, 0x00), gf = DPPF(act, 0x55), gg = DPPF(act, 0xAA), go = DPPF(act, 0xFF);
                    cst = fmaf(gf, cst, gi * gg);
                    float h0new = go * tanhf2_(cst);
                    if (q == 0) h0s[sW][s] = h0new;
                }
                if (u >= 1) {
                    // Wih1 (i,f) partials for L1 step t=u-1
                    float ptv = (q == 1) ? Sb1 : Sb0;
                    if (q < 2) g1ih[u & 1][s][q] = ptv;
                }
            }
            if (tid == 0 && u >= 2 && u <= Tn + 1) tempc[(u - 2) & (CH - 1)] = xprev2;
            xprev2 = xprev; xprev = xv.x;
        } else {
            if (u >= 2 && u <= Tn + 1) {
                // L1 step t = u-2: hh on h1(u-3), ih(g,o) on h0(u-2)
                const float4* hv4 = (const float4*)(&h1s[(u + 1) & 1][q * 16]);
                const float4* xv4 = (const float4*)(&h0s[s2][q * 16]);
                f32x2 A0 = {0,0}, A1 = {0,0}, A2 = {0,0}, A3 = {0,0}, B0 = {0,0}, B1 = {0,0};
                #pragma unroll
                for (int k = 0; k < 4; ++k) {
                    float4 h4 = hv4[k];
                    f32x2 lo = {h4.x, h4.y}, hi = {h4.z, h4.w};
                    pkfma(A0, wA[0  + 2*k], lo); pkfma(A0, wA[1  + 2*k], hi);
                    pkfma(A1, wA[8  + 2*k], lo); pkfma(A1, wA[9  + 2*k], hi);
                    pkfma(A2, wA[16 + 2*k], lo); pkfma(A2, wA[17 + 2*k], hi);
                    pkfma(A3, wA[24 + 2*k], lo); pkfma(A3, wA[25 + 2*k], hi);
                    float4 x4 = xv4[k];
                    f32x2 xlo = {x4.x, x4.y}, xhi = {x4.z, x4.w};
                    pkfma(B0, wB[0  + 2*k], xlo); pkfma(B0, wB[1  + 2*k], xhi);
                    pkfma(B1, wB[8  + 2*k], xlo); pkfma(B1, wB[9  + 2*k], xhi);
                }
                float Sa0 = A0.x + A0.y, Sa1 = A1.x + A1.y, Sa2 = A2.x + A2.y, Sa3 = A3.x + A3.y;
                float Sb0 = B0.x + B0.y, Sb1 = B1.x + B1.y;
                QSUM(Sa0); QSUM(Sa1); QSUM(Sa2); QSUM(Sa3);
                QSUM(Sb0); QSUM(Sb1);
                float ptl = g1ih[(u - 1) & 1][s][q & 1];   // i,f partials from h0-waves
                float ihq = (q < 2) ? ptl : ((q == 2) ? Sb0 : Sb1);
                float val = sel4_(Sa0, Sa1, Sa2, Sa3, q) + ihq + bact;
                float act = fmaf(rcpf_(1.f + __expf(kmul * val)), kk, cc);
                float gi = DPPF(act, 0x00), gf = DPPF(act, 0x55), gg = DPPF(act, 0xAA), go = DPPF(act, 0xFF);
                cst = fmaf(gf, cst, gi * gg);
                float h1new = go * tanhf2_(cst);
                if (q == 0) h1s[u & 1][s] = h1new;
                if (q == 1) h1ring[(u - 2) & (CH - 1)][s] = h1new;
            }
        }
        // rotate h0 slots: next iter writes the slot that held h0(u-2)
        int tmp = s2; s2 = s1; s1 = sW; sW = tmp;
        __syncthreads();
    }
}

extern "C" void kernel_launch(void* const* d_in, const int* in_sizes, int n_in,
                              void* d_out, int out_size, void* d_ws, size_t ws_size,
                              hipStream_t stream) {
    const float* ts   = (const float*)d_in[0];
    const float* sf   = (const float*)d_in[1];
    const float* Wih0 = (const float*)d_in[2];
    const float* Whh0 = (const float*)d_in[3];
    const float* bih0 = (const float*)d_in[4];
    const float* bhh0 = (const float*)d_in[5];
    const float* Wih1 = (const float*)d_in[6];
    const float* Whh1 = (const float*)d_in[7];
    const float* bih1 = (const float*)d_in[8];
    const float* bhh1 = (const float*)d_in[9];
    const float* seW1 = (const float*)d_in[10];
    const float* seb1 = (const float*)d_in[11];
    const float* seW2 = (const float*)d_in[12];
    const float* seb2 = (const float*)d_in[13];
    const float* pbW1 = (const float*)d_in[14];
    const float* pbb1 = (const float*)d_in[15];
    const float* pbW2 = (const float*)d_in[16];
    const float* pbb2 = (const float*)d_in[17];
    const float* pbW3 = (const float*)d_in[18];
    const float* pbb3 = (const float*)d_in[19];
    const float* drW1 = (const float*)d_in[20];
    const float* drb1 = (const float*)d_in[21];
    const float* drW2 = (const float*)d_in[22];
    const float* drb2 = (const float*)d_in[23];
    const float* drW3 = (const float*)d_in[24];
    const float* drb3 = (const float*)d_in[25];
    const float* ruW1 = (const float*)d_in[26];
    const float* rub1 = (const float*)d_in[27];
    const float* ruW2 = (const float*)d_in[28];
    const float* rub2 = (const float*)d_in[29];
    float* out = (float*)d_out;

    fused_rul_kernel<<<dim3(Bn), dim3(NT), 0, stream>>>(
        ts, sf, Wih0, Whh0, bih0, bhh0, Wih1, Whh1, bih1, bhh1,
        seW1, seb1, seW2, seb2, pbW1, pbb1, pbW2, pbb2, pbW3, pbb3,
        drW1, drb1, drW2, drb2, drW3, drb3, ruW1, rub1, ruW2, rub2, out);
}